// Round 11
// baseline (382.864 us; speedup 1.0000x reference)
//
#include <hip/hip_runtime.h>
#include <stdint.h>

typedef __attribute__((ext_vector_type(8))) short short8;
typedef __attribute__((ext_vector_type(4))) float f32x4;

#define HP 130
#define WPAD 258
#define CIN 256

#define AS1 __attribute__((address_space(1)))
#define AS3 __attribute__((address_space(3)))

__device__ __forceinline__ unsigned short f2bf(float f) {
  unsigned int x = __float_as_uint(f);
  x = x + 0x7fffu + ((x >> 16) & 1u);
  return (unsigned short)(x >> 16);
}

// ================= k1: mu-FC | mlpT+bias  (only true upstream deps of build) ===========
// Blocks: [0,140) mu   [140,298) prep
__global__ __launch_bounds__(256) void k_pre(
    const float* __restrict__ sty, const float* __restrict__ fcw,
    const float* __restrict__ fcb, float* __restrict__ mu,
    const float* __restrict__ mlpw, float* __restrict__ mlpT,
    const float* __restrict__ cgb, const float* __restrict__ cbb,
    const float* __restrict__ sgb, const float* __restrict__ sbb,
    const float* __restrict__ blg, const float* __restrict__ blb,
    float* __restrict__ bias)
{
  int bid = blockIdx.x, tid = threadIdx.x;
  if (bid < 140) {
    int b = bid / 35, j = bid - 35 * b;
    __shared__ float ss[128];
    if (tid < 128) ss[tid] = sty[((size_t)b * 35 + j) * 128 + tid];
    __syncthreads();
    if (tid < 128) {
      int o = tid;
      const float4* wr = (const float4*)(fcw + ((size_t)j * 128 + o) * 128);
      const float4* sv = (const float4*)ss;
      float acc = fcb[j * 128 + o];
      #pragma unroll 8
      for (int d = 0; d < 32; ++d) {
        float4 wv = wr[d], s4 = sv[d];
        acc += wv.x * s4.x + wv.y * s4.y + wv.z * s4.z + wv.w * s4.w;
      }
      mu[((size_t)b * 35 + j) * 128 + o] = fmaxf(acc, 0.f);
    }
  } else {
    int t = (bid - 140) * 256 + tid;
    if (t < 40320) {
      int o = t & 127;
      int jt = t >> 7;                    // j*9 + tap
      mlpT[(size_t)jt * 128 + o] = mlpw[((size_t)o * 35 + (jt / 9)) * 9 + (jt % 9)];
    }
    if (t < 256) {
      float ga = 1.f / (1.f + expf(-blg[0]));
      float ba = 1.f / (1.f + expf(-blb[0]));
      bias[t]       = ga * cgb[t] + (1.f - ga) * sgb[t];
      bias[256 + t] = ba * cbb[t] + (1.f - ba) * sbb[t];
    }
  }
}

// ================= k2: IN-stats | build U | halo-zero | weight-pack  (all independent) ==
// Blocks: [0,1024) stats   [1024,17408) build   [17408,17795) halo   [17795,18371) pack
__global__ __launch_bounds__(256) void k_mid(
    const float* __restrict__ x, float* __restrict__ stats,
    const int* __restrict__ seg, const float* __restrict__ mu,
    const float* __restrict__ mlpT, const float* __restrict__ mlpb,
    unsigned short* __restrict__ U,
    const float* __restrict__ cgw, const float* __restrict__ cbw,
    const float* __restrict__ sgw, const float* __restrict__ sbw,
    const float* __restrict__ blg, const float* __restrict__ blb,
    unsigned short* __restrict__ Wp)
{
  int bid = blockIdx.x, t = threadIdx.x;
  if (bid < 1024) {
    int bc = bid;
    const float* p = x + (size_t)bc * 32768;
    float s = 0.f, s2 = 0.f;
    #pragma unroll 4
    for (int i = 0; i < 32; ++i) {
      float4 v = *(const float4*)(p + (size_t)i * 1024 + t * 4);
      s  += v.x + v.y + v.z + v.w;
      s2 += v.x * v.x + v.y * v.y + v.z * v.z + v.w * v.w;
    }
    #pragma unroll
    for (int off2 = 32; off2 > 0; off2 >>= 1) {
      s  += __shfl_down(s, off2);
      s2 += __shfl_down(s2, off2);
    }
    __shared__ float red[8];
    int lane = t & 63, wv = t >> 6;
    if (lane == 0) { red[wv] = s; red[4 + wv] = s2; }
    __syncthreads();
    if (t == 0) {
      float S  = red[0] + red[1] + red[2] + red[3];
      float S2 = red[4] + red[5] + red[6] + red[7];
      float mean = S * (1.f / 32768.f);
      float var  = S2 * (1.f / 32768.f) - mean * mean;
      stats[bc] = mean;
      stats[1024 + bc] = rsqrtf(var + 1e-5f);
    }
  } else if (bid < 17408) {
    int blk = bid - 1024;               // 16384
    int b = blk >> 12, rem = blk & 4095;
    int h = rem >> 5, w0 = (rem & 31) << 3;
    int p = t >> 5, q = t & 31;
    int w = w0 + p;
    unsigned short* up = U + (((size_t)(b * HP + h + 1)) * WPAD + (w + 1)) * CIN;
    union { uint4 v4; unsigned short s[8]; } u;
    if (q < 16) {
      int lab = seg[((size_t)b * 128 + h) * 256 + w];
      const float4* mrow = (const float4*)(mu + ((size_t)(b * 35 + lab)) * 128 + q * 8);
      float4 v0 = mrow[0], v1 = mrow[1];
      u.s[0] = f2bf(v0.x); u.s[1] = f2bf(v0.y); u.s[2] = f2bf(v0.z); u.s[3] = f2bf(v0.w);
      u.s[4] = f2bf(v1.x); u.s[5] = f2bf(v1.y); u.s[6] = f2bf(v1.z); u.s[7] = f2bf(v1.w);
      *(uint4*)(up + q * 8) = u.v4;
    } else {
      int o0 = (q - 16) * 8;
      float a[8];
      #pragma unroll
      for (int j = 0; j < 8; ++j) a[j] = mlpb[o0 + j];
      #pragma unroll
      for (int kh = 0; kh < 3; ++kh) {
        int hh = h + kh - 1;
        if ((unsigned)hh < 128u) {
          #pragma unroll
          for (int kw = 0; kw < 3; ++kw) {
            int ww = w + kw - 1;
            if ((unsigned)ww < 256u) {
              int lab2 = seg[((size_t)b * 128 + hh) * 256 + ww];
              const float4* wr = (const float4*)(mlpT + ((size_t)lab2 * 9 + kh * 3 + kw) * 128 + o0);
              float4 v0 = wr[0], v1 = wr[1];
              a[0] += v0.x; a[1] += v0.y; a[2] += v0.z; a[3] += v0.w;
              a[4] += v1.x; a[5] += v1.y; a[6] += v1.z; a[7] += v1.w;
            }
          }
        }
      }
      #pragma unroll
      for (int j = 0; j < 8; ++j) u.s[j] = f2bf(fmaxf(a[j], 0.f));
      *(uint4*)(up + 128 + o0) = u.v4;
    }
  } else if (bid < 17795) {
    int tt = (bid - 17408) * 256 + t;
    if (tt >= 98816) return;            // 3088 halo pixels * 32 uint4
    int sub = tt & 31, pi = tt >> 5;
    int b = pi / 772, r = pi - b * 772;
    int h, w;
    if (r < 258)      { h = 0;   w = r; }
    else if (r < 516) { h = 129; w = r - 258; }
    else if (r < 644) { h = r - 516 + 1; w = 0; }
    else              { h = r - 644 + 1; w = 257; }
    ((uint4*)U)[((size_t)(b * HP + h) * WPAD + w) * 32 + sub] = (uint4){0, 0, 0, 0};
  } else {
    // ---- packed, blended bf16 weights: [vfpair(16)][cc(8)][tap(9)][mf(2)][lane(64)] x16B
    // vf = vfpair*2+mf (16v each); v = vf*16+(lane&15); k-index = cc*32 + 8*(lane>>4) + j
    int gid = (bid - 17795) * 256 + t;  // 147456 exactly
    int lane = gid & 63;
    int cc = (gid >> 6) & 7;
    int rest = gid >> 9;                // vf*9 + tap
    int tap = rest % 9;
    int vf = rest / 9;
    int v = vf * 16 + (lane & 15);
    int c = v >> 1, g = v & 1;
    int ci0 = cc * 32 + (lane >> 4) * 8;
    float ga = 1.f / (1.f + expf(-blg[0]));
    float ba = 1.f / (1.f + expf(-blb[0]));
    float sc = g ? ba : ga;
    const float* wavg = g ? cbw : cgw;
    const float* wsp  = g ? sbw : sgw;
    union { uint4 v4; unsigned short s[8]; } u;
    #pragma unroll
    for (int jj = 0; jj < 8; ++jj) {
      int ci = ci0 + jj;
      float val;
      if (ci < 128) val = sc * wavg[((size_t)c * 128 + ci) * 9 + tap];
      else          val = (1.f - sc) * wsp[((size_t)c * 128 + (ci - 128)) * 9 + tap];
      u.s[jj] = f2bf(val);
    }
    int vfpair = vf >> 1, mfi = vf & 1;
    uint4* dst = (uint4*)Wp + ((size_t)(((vfpair * 8 + cc) * 9 + tap) * 2 + mfi)) * 64 + lane;
    *dst = u.v4;
  }
}

// ---------------- main fused conv: 4 waves x (32v x 128px) = 128v x 128px per block ----
// Wave tile 32v x 128px: acc = 64 AGPR (half of R7) at UNCHANGED A-bytes/FLOP (1/128)
// -> 3 waves/SIMD occupancy without R4's vmem wall. Linear LDS layout (R8-style):
// slot L = (r*4+sl)*130 + px -> B reads lane-contiguous (conflict-free, no swizzle),
// all B offsets compile-time. Counted-vmcnt FIFO re-derived for 2-wide A-loads:
// steady vmcnt(4); every STG keeps a 2-tap completion window; never drains mid-loop.

#define WAITV_(vm, lg) asm volatile("s_waitcnt vmcnt(" #vm ") lgkmcnt(" #lg ")" ::: "memory")
#define WAITV(vm, lg) do { WAITV_(vm, lg); __builtin_amdgcn_sched_barrier(0); } while (0)
#define WAITL(lg) do { asm volatile("s_waitcnt lgkmcnt(" #lg ")" ::: "memory"); __builtin_amdgcn_sched_barrier(0); } while (0)

#define MM(AS, BS, H) do {                                                     \
    __builtin_amdgcn_s_setprio(1);                                             \
    _Pragma("unroll")                                                          \
    for (int mf_ = 0; mf_ < 2; ++mf_)                                          \
      _Pragma("unroll")                                                        \
      for (int nf_ = 0; nf_ < 4; ++nf_)                                        \
        acc[mf_][(H) * 4 + nf_] = __builtin_amdgcn_mfma_f32_16x16x32_bf16(     \
            afr##AS[mf_], bfr##BS[nf_], acc[mf_][(H) * 4 + nf_], 0, 0, 0);     \
    __builtin_amdgcn_s_setprio(0);                                             \
  } while (0)

#define LOADA(NS) do {                                                         \
    aptr += 2048;                                                              \
    afr##NS[0] = *(const short8*)(aptr);                                       \
    afr##NS[1] = *(const short8*)(aptr + 1024);                                \
  } while (0)

#define BOFF(T, H) (((T) / 3) * 8320 + ((T) % 3) * 16 + (H) * 1024)
#define LOADB(NS, T, H) do {                                                   \
    bfr##NS[0] = *(const short8*)(lbuf + pbase + BOFF(T, H));                  \
    bfr##NS[1] = *(const short8*)(lbuf + pbase + BOFF(T, H) + 256);            \
    bfr##NS[2] = *(const short8*)(lbuf + pbase + BOFF(T, H) + 512);            \
    bfr##NS[3] = *(const short8*)(lbuf + pbase + BOFF(T, H) + 768);            \
  } while (0)

#define STG(SI) do {                                                           \
    __builtin_amdgcn_global_load_lds((const AS1 unsigned int*)gsrc[SI],        \
        (AS3 unsigned int*)((SI) < 6 ? (stbw + (SI) * 4096) : (stb + 24576)),  \
        16, 0, 0);                                                             \
    gsrc[SI] += 64;                                                            \
  } while (0)

__global__ __launch_bounds__(256, 3) void k_conv(
    const float* __restrict__ x, const uint4* __restrict__ U,
    const char* __restrict__ Wp, const float* __restrict__ bias,
    const float* __restrict__ stats, float* __restrict__ out)
{
  int bid = blockIdx.x;                // 4096
  int xcd = bid & 7, i0 = bid >> 3;    // i0: 0..511
  int pt = xcd * 128 + (i0 >> 2);      // mt fastest within an XCD (4 mt share U slice)
  int mt = i0 & 3;
  int b = pt >> 8, rem = pt & 255;
  int h0 = rem >> 1, w0 = (rem & 1) << 7;
  int tid = threadIdx.x;
  int lane = tid & 63, wid = tid >> 6;
  int lo = lane & 15, hi = lane >> 4;

  __shared__ uint4 Ubuf[2][1600];   // 1560 used slots (+pad) per buffer

  // staging sources; LDS slot L = (r*4+sl)*130 + px holds U[h0+r][w0+px][cc*32+sl*8..+8]
  const char* gsrc[7];
  #pragma unroll
  for (int i = 0; i < 7; ++i) {
    int row = (i < 6) ? (wid + 4 * i) : 24;
    int L = row * 64 + lane;
    int rsl = L / 130, px = L - rsl * 130;
    int r = rsl >> 2, sl = rsl & 3;          // r==3 only for pad slots (U over-alloc'd)
    gsrc[i] = (const char*)U +
        (size_t)(((b * HP + h0 + r) * WPAD + (w0 + px)) * CIN + sl * 8) * 2;
  }

  f32x4 acc[2][8];                     // 64 AGPR
  #pragma unroll
  for (int i = 0; i < 2; ++i)
    #pragma unroll
    for (int j = 0; j < 8; ++j) acc[i][j] = (f32x4){0.f, 0.f, 0.f, 0.f};

  // A stream: sequential 2 KB per (cc,tap); each wave owns vfpair = mt*4 + wid (32v)
  int vfpair = mt * 4 + wid;
  const char* aptr = Wp + (size_t)vfpair * 147456 + lane * 16;

  // B base: lane l reads slot (kh*4+hi)*130 + kw + px, px = H*64 + nf*16 + lo
  int pbase = hi * 2080 + lo * 16;

  const char* lbuf = (const char*)&Ubuf[0][0];
  char* stb = (char*)&Ubuf[1][0];

  // prologue: stage buffer 0 (cc=0), then A(0)
  {
    char* stb0 = (char*)&Ubuf[0][0];
    char* stbw0 = stb0 + wid * 1024;
    #pragma unroll
    for (int i = 0; i < 7; ++i) {
      __builtin_amdgcn_global_load_lds((const AS1 unsigned int*)gsrc[i],
          (AS3 unsigned int*)(i < 6 ? (stbw0 + i * 4096) : (stb0 + 24576)), 16, 0, 0);
      gsrc[i] += 64;
    }
  }
  short8 afr0[2], afr1[2], bfr0[4], bfr1[4];
  afr0[0] = *(const short8*)(aptr);
  afr0[1] = *(const short8*)(aptr + 1024);
  WAITV(2, 0);                      // 7 stage rows done; A(0)x2 may stay in flight
  __builtin_amdgcn_s_barrier();

  #pragma unroll 1
  for (int cc = 0; cc < 7; ++cc) {
    char* stbw = stb + wid * 1024;
    LOADB(0, 0, 0);
    // t=0: entry {A0x2}; drain A0, allow {A1x2, S0}
    LOADA(1); STG(0); LOADB(1, 0, 1); WAITV(3, 4); MM(0, 0, 0);
              LOADB(0, 1, 0);        WAITL(4);     MM(0, 1, 1);
    // t=1..6 steady: drain A(t)x2 (+ S(t-2) if present); S(t-1) survives -> 2-tap windows
    LOADA(0); STG(1); LOADB(1, 1, 1); WAITV(4, 4); MM(1, 0, 0);
              LOADB(0, 2, 0);        WAITL(4);     MM(1, 1, 1);
    LOADA(1); STG(2); LOADB(1, 2, 1); WAITV(4, 4); MM(0, 0, 0);
              LOADB(0, 3, 0);        WAITL(4);     MM(0, 1, 1);
    LOADA(0); STG(3); LOADB(1, 3, 1); WAITV(4, 4); MM(1, 0, 0);
              LOADB(0, 4, 0);        WAITL(4);     MM(1, 1, 1);
    LOADA(1); STG(4); LOADB(1, 4, 1); WAITV(4, 4); MM(0, 0, 0);
              LOADB(0, 5, 0);        WAITL(4);     MM(0, 1, 1);
    LOADA(0); STG(5); LOADB(1, 5, 1); WAITV(4, 4); MM(1, 0, 0);
              LOADB(0, 6, 0);        WAITL(4);     MM(1, 1, 1);
    LOADA(1); STG(6); LOADB(1, 6, 1); WAITV(4, 4); MM(0, 0, 0);
              LOADB(0, 7, 0);        WAITL(4);     MM(0, 1, 1);
    // t=7: no STG; drain {S5, A7x2}, leave {S6, A8x2}
    LOADA(0);         LOADB(1, 7, 1); WAITV(3, 4); MM(1, 0, 0);
              LOADB(0, 8, 0);        WAITL(4);     MM(1, 1, 1);
    // t=8: prefetch next cc's A(0); drain {S6, A8x2} pre-barrier, leave A0'x2 in flight
    LOADA(1);         LOADB(1, 8, 1); WAITV(2, 4); MM(0, 0, 0);
                                     WAITV(2, 0);  MM(0, 1, 1);
    __builtin_amdgcn_s_barrier();
    { const char* tmp = lbuf; lbuf = (const char*)stb; stb = (char*)tmp; }
    { short8 t0 = afr1[0]; afr0[0] = t0; t0 = afr1[1]; afr0[1] = t0; }
  }
  // peeled cc = 7 (no staging, no barrier)
  {
    LOADB(0, 0, 0);
    LOADA(1); LOADB(1, 0, 1); WAITV(2, 4); MM(0, 0, 0);
              LOADB(0, 1, 0); WAITL(4);    MM(0, 1, 1);
    LOADA(0); LOADB(1, 1, 1); WAITV(2, 4); MM(1, 0, 0);
              LOADB(0, 2, 0); WAITL(4);    MM(1, 1, 1);
    LOADA(1); LOADB(1, 2, 1); WAITV(2, 4); MM(0, 0, 0);
              LOADB(0, 3, 0); WAITL(4);    MM(0, 1, 1);
    LOADA(0); LOADB(1, 3, 1); WAITV(2, 4); MM(1, 0, 0);
              LOADB(0, 4, 0); WAITL(4);    MM(1, 1, 1);
    LOADA(1); LOADB(1, 4, 1); WAITV(2, 4); MM(0, 0, 0);
              LOADB(0, 5, 0); WAITL(4);    MM(0, 1, 1);
    LOADA(0); LOADB(1, 5, 1); WAITV(2, 4); MM(1, 0, 0);
              LOADB(0, 6, 0); WAITL(4);    MM(1, 1, 1);
    LOADA(1); LOADB(1, 6, 1); WAITV(2, 4); MM(0, 0, 0);
              LOADB(0, 7, 0); WAITL(4);    MM(0, 1, 1);
    LOADA(0); LOADB(1, 7, 1); WAITV(2, 4); MM(1, 0, 0);
              LOADB(0, 8, 0); WAITL(4);    MM(1, 1, 1);
              LOADB(1, 8, 1); WAITV(0, 4); MM(0, 0, 0);
                              WAITL(0);    MM(0, 1, 1);
  }

  // epilogue: bias + instance-norm + blend; C/D: col=lane&15, row=(lane>>4)*4+reg
  #pragma unroll
  for (int mf = 0; mf < 2; ++mf) {
    int vbase = vfpair * 32 + mf * 16 + hi * 4;
    #pragma unroll
    for (int p = 0; p < 2; ++p) {
      int c = (vbase >> 1) + p;
      float bg = bias[c], bb = bias[256 + c];
      float mean = stats[b * 256 + c], rs = stats[1024 + b * 256 + c];
      const float* xrow = x + ((size_t)(b * 256 + c) * 128 + h0) * 256 + w0;
      float* orow = out + ((size_t)(b * 256 + c) * 128 + h0) * 256 + w0;
      #pragma unroll
      for (int nf = 0; nf < 8; ++nf) {
        int pix = nf * 16 + lo;
        float g  = acc[mf][nf][2 * p]     + bg;
        float bt = acc[mf][nf][2 * p + 1] + bb;
        float xv = xrow[pix];
        orow[pix] = (xv - mean) * rs * (1.f + g) + bt;
      }
    }
  }
}

extern "C" void kernel_launch(void* const* d_in, const int* in_sizes, int n_in,
                              void* d_out, int out_size, void* d_ws, size_t ws_size,
                              hipStream_t stream)
{
  const float* x    = (const float*)d_in[0];
  const int*   seg  = (const int*)d_in[1];
  const float* sty  = (const float*)d_in[2];
  const float* fcw  = (const float*)d_in[3];
  const float* fcb  = (const float*)d_in[4];
  const float* cgw  = (const float*)d_in[5];
  const float* cgb  = (const float*)d_in[6];
  const float* cbw  = (const float*)d_in[7];
  const float* cbb  = (const float*)d_in[8];
  const float* mlpw = (const float*)d_in[9];
  const float* mlpb = (const float*)d_in[10];
  const float* sgw  = (const float*)d_in[11];
  const float* sgb  = (const float*)d_in[12];
  const float* sbw  = (const float*)d_in[13];
  const float* sbb  = (const float*)d_in[14];
  const float* blg  = (const float*)d_in[15];
  const float* blb  = (const float*)d_in[16];
  float* out = (float*)d_out;

  char* ws = (char*)d_ws;
  const size_t U_BYTES = (size_t)4 * HP * WPAD * CIN * 2;   // 68,689,920
  size_t off = 0;
  unsigned short* U = (unsigned short*)(ws + off); off += U_BYTES + 262144;  // pad: overshoot reads
  char* Wp   = ws + off;           off += (size_t)512 * 256 * 9 * 2;  // 2,359,296
  float* mu  = (float*)(ws + off); off += (size_t)4 * 35 * 128 * 4;   // 71,680
  float* mlpT= (float*)(ws + off); off += (size_t)35 * 9 * 128 * 4;   // 161,280
  float* bias= (float*)(ws + off); off += 2048;
  float* stats=(float*)(ws + off); off += 8192;
  if (ws_size < off) return;

  k_pre <<<dim3(298),   dim3(256), 0, stream>>>(
      sty, fcw, fcb, mu, mlpw, mlpT, cgb, cbb, sgb, sbb, blg, blb, bias);
  k_mid <<<dim3(18371), dim3(256), 0, stream>>>(
      x, stats, seg, mu, mlpT, mlpb, U, cgw, cbw, sgw, sbw, blg, blb,
      (unsigned short*)Wp);
  k_conv<<<dim3(4096),  dim3(256), 0, stream>>>(
      x, (const uint4*)U, Wp, bias, stats, out);
}

// Round 12
// 336.835 us; speedup vs baseline: 1.1367x; 1.1367x over previous
//
#include <hip/hip_runtime.h>
#include <stdint.h>

typedef __attribute__((ext_vector_type(8))) short short8;
typedef __attribute__((ext_vector_type(4))) float f32x4;

#define HP 130
#define WPAD 258
#define CIN 256

#define AS1 __attribute__((address_space(1)))
#define AS3 __attribute__((address_space(3)))

__device__ __forceinline__ unsigned short f2bf(float f) {
  unsigned int x = __float_as_uint(f);
  x = x + 0x7fffu + ((x >> 16) & 1u);
  return (unsigned short)(x >> 16);
}

// ================= k1: mu-FC | mlpT+bias  (only true upstream deps of build) ===========
// Blocks: [0,140) mu   [140,298) prep
__global__ __launch_bounds__(256) void k_pre(
    const float* __restrict__ sty, const float* __restrict__ fcw,
    const float* __restrict__ fcb, float* __restrict__ mu,
    const float* __restrict__ mlpw, float* __restrict__ mlpT,
    const float* __restrict__ cgb, const float* __restrict__ cbb,
    const float* __restrict__ sgb, const float* __restrict__ sbb,
    const float* __restrict__ blg, const float* __restrict__ blb,
    float* __restrict__ bias)
{
  int bid = blockIdx.x, tid = threadIdx.x;
  if (bid < 140) {
    int b = bid / 35, j = bid - 35 * b;
    __shared__ float ss[128];
    if (tid < 128) ss[tid] = sty[((size_t)b * 35 + j) * 128 + tid];
    __syncthreads();
    if (tid < 128) {
      int o = tid;
      const float4* wr = (const float4*)(fcw + ((size_t)j * 128 + o) * 128);
      const float4* sv = (const float4*)ss;
      float acc = fcb[j * 128 + o];
      #pragma unroll 8
      for (int d = 0; d < 32; ++d) {
        float4 wv = wr[d], s4 = sv[d];
        acc += wv.x * s4.x + wv.y * s4.y + wv.z * s4.z + wv.w * s4.w;
      }
      mu[((size_t)b * 35 + j) * 128 + o] = fmaxf(acc, 0.f);
    }
  } else {
    int t = (bid - 140) * 256 + tid;
    if (t < 40320) {
      int o = t & 127;
      int jt = t >> 7;                    // j*9 + tap
      mlpT[(size_t)jt * 128 + o] = mlpw[((size_t)o * 35 + (jt / 9)) * 9 + (jt % 9)];
    }
    if (t < 256) {
      float ga = 1.f / (1.f + expf(-blg[0]));
      float ba = 1.f / (1.f + expf(-blb[0]));
      bias[t]       = ga * cgb[t] + (1.f - ga) * sgb[t];
      bias[256 + t] = ba * cbb[t] + (1.f - ba) * sbb[t];
    }
  }
}

// ================= k2: IN-stats | build U | halo-zero | weight-pack  (all independent) ==
// Blocks: [0,1024) stats   [1024,17408) build   [17408,17795) halo   [17795,18371) pack
__global__ __launch_bounds__(256) void k_mid(
    const float* __restrict__ x, float* __restrict__ stats,
    const int* __restrict__ seg, const float* __restrict__ mu,
    const float* __restrict__ mlpT, const float* __restrict__ mlpb,
    unsigned short* __restrict__ U,
    const float* __restrict__ cgw, const float* __restrict__ cbw,
    const float* __restrict__ sgw, const float* __restrict__ sbw,
    const float* __restrict__ blg, const float* __restrict__ blb,
    unsigned short* __restrict__ Wp)
{
  int bid = blockIdx.x, t = threadIdx.x;
  if (bid < 1024) {
    int bc = bid;
    const float* p = x + (size_t)bc * 32768;
    float s = 0.f, s2 = 0.f;
    #pragma unroll 4
    for (int i = 0; i < 32; ++i) {
      float4 v = *(const float4*)(p + (size_t)i * 1024 + t * 4);
      s  += v.x + v.y + v.z + v.w;
      s2 += v.x * v.x + v.y * v.y + v.z * v.z + v.w * v.w;
    }
    #pragma unroll
    for (int off2 = 32; off2 > 0; off2 >>= 1) {
      s  += __shfl_down(s, off2);
      s2 += __shfl_down(s2, off2);
    }
    __shared__ float red[8];
    int lane = t & 63, wv = t >> 6;
    if (lane == 0) { red[wv] = s; red[4 + wv] = s2; }
    __syncthreads();
    if (t == 0) {
      float S  = red[0] + red[1] + red[2] + red[3];
      float S2 = red[4] + red[5] + red[6] + red[7];
      float mean = S * (1.f / 32768.f);
      float var  = S2 * (1.f / 32768.f) - mean * mean;
      stats[bc] = mean;
      stats[1024 + bc] = rsqrtf(var + 1e-5f);
    }
  } else if (bid < 17408) {
    int blk = bid - 1024;               // 16384
    int b = blk >> 12, rem = blk & 4095;
    int h = rem >> 5, w0 = (rem & 31) << 3;
    int p = t >> 5, q = t & 31;
    int w = w0 + p;
    unsigned short* up = U + (((size_t)(b * HP + h + 1)) * WPAD + (w + 1)) * CIN;
    union { uint4 v4; unsigned short s[8]; } u;
    if (q < 16) {
      int lab = seg[((size_t)b * 128 + h) * 256 + w];
      const float4* mrow = (const float4*)(mu + ((size_t)(b * 35 + lab)) * 128 + q * 8);
      float4 v0 = mrow[0], v1 = mrow[1];
      u.s[0] = f2bf(v0.x); u.s[1] = f2bf(v0.y); u.s[2] = f2bf(v0.z); u.s[3] = f2bf(v0.w);
      u.s[4] = f2bf(v1.x); u.s[5] = f2bf(v1.y); u.s[6] = f2bf(v1.z); u.s[7] = f2bf(v1.w);
      *(uint4*)(up + q * 8) = u.v4;
    } else {
      int o0 = (q - 16) * 8;
      float a[8];
      #pragma unroll
      for (int j = 0; j < 8; ++j) a[j] = mlpb[o0 + j];
      #pragma unroll
      for (int kh = 0; kh < 3; ++kh) {
        int hh = h + kh - 1;
        if ((unsigned)hh < 128u) {
          #pragma unroll
          for (int kw = 0; kw < 3; ++kw) {
            int ww = w + kw - 1;
            if ((unsigned)ww < 256u) {
              int lab2 = seg[((size_t)b * 128 + hh) * 256 + ww];
              const float4* wr = (const float4*)(mlpT + ((size_t)lab2 * 9 + kh * 3 + kw) * 128 + o0);
              float4 v0 = wr[0], v1 = wr[1];
              a[0] += v0.x; a[1] += v0.y; a[2] += v0.z; a[3] += v0.w;
              a[4] += v1.x; a[5] += v1.y; a[6] += v1.z; a[7] += v1.w;
            }
          }
        }
      }
      #pragma unroll
      for (int j = 0; j < 8; ++j) u.s[j] = f2bf(fmaxf(a[j], 0.f));
      *(uint4*)(up + 128 + o0) = u.v4;
    }
  } else if (bid < 17795) {
    int tt = (bid - 17408) * 256 + t;
    if (tt >= 98816) return;            // 3088 halo pixels * 32 uint4
    int sub = tt & 31, pi = tt >> 5;
    int b = pi / 772, r = pi - b * 772;
    int h, w;
    if (r < 258)      { h = 0;   w = r; }
    else if (r < 516) { h = 129; w = r - 258; }
    else if (r < 644) { h = r - 516 + 1; w = 0; }
    else              { h = r - 644 + 1; w = 257; }
    ((uint4*)U)[((size_t)(b * HP + h) * WPAD + w) * 32 + sub] = (uint4){0, 0, 0, 0};
  } else {
    // ---- packed, blended bf16 weights: [vfpair(16)][cc(8)][tap(9)][mf(2)][lane(64)] x16B
    // vf = vfpair*2+mf (16v each); v = vf*16+(lane&15); k-index = cc*32 + 8*(lane>>4) + j
    int gid = (bid - 17795) * 256 + t;  // 147456 exactly
    int lane = gid & 63;
    int cc = (gid >> 6) & 7;
    int rest = gid >> 9;                // vf*9 + tap
    int tap = rest % 9;
    int vf = rest / 9;
    int v = vf * 16 + (lane & 15);
    int c = v >> 1, g = v & 1;
    int ci0 = cc * 32 + (lane >> 4) * 8;
    float ga = 1.f / (1.f + expf(-blg[0]));
    float ba = 1.f / (1.f + expf(-blb[0]));
    float sc = g ? ba : ga;
    const float* wavg = g ? cbw : cgw;
    const float* wsp  = g ? sbw : sgw;
    union { uint4 v4; unsigned short s[8]; } u;
    #pragma unroll
    for (int jj = 0; jj < 8; ++jj) {
      int ci = ci0 + jj;
      float val;
      if (ci < 128) val = sc * wavg[((size_t)c * 128 + ci) * 9 + tap];
      else          val = (1.f - sc) * wsp[((size_t)c * 128 + (ci - 128)) * 9 + tap];
      u.s[jj] = f2bf(val);
    }
    int vfpair = vf >> 1, mfi = vf & 1;
    uint4* dst = (uint4*)Wp + ((size_t)(((vfpair * 8 + cc) * 9 + tap) * 2 + mfi)) * 64 + lane;
    *dst = u.v4;
  }
}

// ---------------- main fused conv: 4 waves x (32v x 128px) = 128v x 128px per block ----
// R11 3-wave structure + R7's MEASURED-conflict-free LDS layout (pixel-major + XOR
// swizzle: slot s' = s ^ ((P>>1)&3), applied on global source at staging AND on read).
// R11's [rsl][px] layout put 16-lane groups at 2080-B stride -> 3.8e7 bank conflicts.
// Counted vmcnt for 2-wide A-loads: steady vmcnt(4); STGs keep 2-tap windows.

#define WAITV_(vm, lg) asm volatile("s_waitcnt vmcnt(" #vm ") lgkmcnt(" #lg ")" ::: "memory")
#define WAITV(vm, lg) do { WAITV_(vm, lg); __builtin_amdgcn_sched_barrier(0); } while (0)
#define WAITL(lg) do { asm volatile("s_waitcnt lgkmcnt(" #lg ")" ::: "memory"); __builtin_amdgcn_sched_barrier(0); } while (0)

#define MM(AS, BS, H) do {                                                     \
    __builtin_amdgcn_s_setprio(1);                                             \
    _Pragma("unroll")                                                          \
    for (int mf_ = 0; mf_ < 2; ++mf_)                                          \
      _Pragma("unroll")                                                        \
      for (int nf_ = 0; nf_ < 4; ++nf_)                                        \
        acc[mf_][(H) * 4 + nf_] = __builtin_amdgcn_mfma_f32_16x16x32_bf16(     \
            afr##AS[mf_], bfr##BS[nf_], acc[mf_][(H) * 4 + nf_], 0, 0, 0);     \
    __builtin_amdgcn_s_setprio(0);                                             \
  } while (0)

#define LOADA(NS) do {                                                         \
    aptr += 2048;                                                              \
    afr##NS[0] = *(const short8*)(aptr);                                       \
    afr##NS[1] = *(const short8*)(aptr + 1024);                                \
  } while (0)

#define LOADB(NS, T, H) do {                                                   \
    bfr##NS[0] = *(const short8*)(lbuf + off[T] + (H) * 4096);                 \
    bfr##NS[1] = *(const short8*)(lbuf + off[T] + (H) * 4096 + 1024);          \
    bfr##NS[2] = *(const short8*)(lbuf + off[T] + (H) * 4096 + 2048);          \
    bfr##NS[3] = *(const short8*)(lbuf + off[T] + (H) * 4096 + 3072);          \
  } while (0)

#define STG(SI) do {                                                           \
    __builtin_amdgcn_global_load_lds((const AS1 unsigned int*)gsrc[SI],        \
        (AS3 unsigned int*)((SI) < 6 ? (stbw + (SI) * 4096) : (stb + 24576)),  \
        16, 0, 0);                                                             \
    gsrc[SI] += 64;                                                            \
  } while (0)

__global__ __launch_bounds__(256, 3) void k_conv(
    const float* __restrict__ x, const uint4* __restrict__ U,
    const char* __restrict__ Wp, const float* __restrict__ bias,
    const float* __restrict__ stats, float* __restrict__ out)
{
  int bid = blockIdx.x;                // 4096
  int xcd = bid & 7, i0 = bid >> 3;    // i0: 0..511
  int pt = xcd * 128 + (i0 >> 2);      // mt fastest within an XCD (4 mt share U slice)
  int mt = i0 & 3;
  int b = pt >> 8, rem = pt & 255;
  int h0 = rem >> 1, w0 = (rem & 1) << 7;
  int tid = threadIdx.x;
  int lane = tid & 63, wid = tid >> 6;
  int lo = lane & 15, hi = lane >> 4;

  __shared__ uint4 Ubuf[2][1600];   // 25 rows of 1 KB (+pad) per buffer

  // staging sources, R7 swizzled mapping: LDS uint4 slot L: P = L>>2, phys sp = L&3,
  // logical ci-slot sl = sp ^ ((P>>1)&3); P = r*130 + pix.
  const char* gsrc[7];
  #pragma unroll
  for (int i = 0; i < 7; ++i) {
    int row = (i < 6) ? (wid + 4 * i) : 24;
    int slot = row * 64 + lane;
    int P = slot >> 2, sp = slot & 3;
    int sl = sp ^ ((P >> 1) & 3);
    int r = P / 130, pix = P - r * 130;     // r==3 only for row-24 pad lanes (U over-alloc'd)
    gsrc[i] = (const char*)U +
        (size_t)(((b * HP + h0 + r) * WPAD + (w0 + pix)) * CIN + sl * 8) * 2;
  }

  f32x4 acc[2][8];                     // 64 AGPR
  #pragma unroll
  for (int i = 0; i < 2; ++i)
    #pragma unroll
    for (int j = 0; j < 8; ++j) acc[i][j] = (f32x4){0.f, 0.f, 0.f, 0.f};

  // A stream: sequential 2 KB per (cc,tap); each wave owns vfpair = mt*4 + wid (32v)
  int vfpair = mt * 4 + wid;
  const char* aptr = Wp + (size_t)vfpair * 147456 + lane * 16;

  // B read offsets per tap (pixel base = lo; H adds 4096 B, nf adds 1024 B;
  // swizzle invariant in nf AND H: +16/+64 shift P>>1 by 8/32 == 0 mod 4)
  int off[9];
  #pragma unroll
  for (int t = 0; t < 9; ++t) {
    int Pb = (t / 3) * 130 + (t % 3) + lo;
    off[t] = Pb * 64 + ((hi ^ ((Pb >> 1) & 3)) << 4);
  }

  const char* lbuf = (const char*)&Ubuf[0][0];
  char* stb = (char*)&Ubuf[1][0];

  // prologue: stage buffer 0 (cc=0), then A(0)
  {
    char* stb0 = (char*)&Ubuf[0][0];
    char* stbw0 = stb0 + wid * 1024;
    #pragma unroll
    for (int i = 0; i < 7; ++i) {
      __builtin_amdgcn_global_load_lds((const AS1 unsigned int*)gsrc[i],
          (AS3 unsigned int*)(i < 6 ? (stbw0 + i * 4096) : (stb0 + 24576)), 16, 0, 0);
      gsrc[i] += 64;
    }
  }
  short8 afr0[2], afr1[2], bfr0[4], bfr1[4];
  afr0[0] = *(const short8*)(aptr);
  afr0[1] = *(const short8*)(aptr + 1024);
  WAITV(2, 0);                      // 7 stage rows done; A(0)x2 may stay in flight
  __builtin_amdgcn_s_barrier();

  #pragma unroll 1
  for (int cc = 0; cc < 7; ++cc) {
    char* stbw = stb + wid * 1024;
    LOADB(0, 0, 0);
    // t=0: entry {A0x2}; drain A0, allow {A1x2, S0}
    LOADA(1); STG(0); LOADB(1, 0, 1); WAITV(3, 4); MM(0, 0, 0);
              LOADB(0, 1, 0);        WAITL(4);     MM(0, 1, 1);
    // t=1..6 steady: drain A(t)x2 (+ S(t-2) if present); S(t-1) survives -> 2-tap windows
    LOADA(0); STG(1); LOADB(1, 1, 1); WAITV(4, 4); MM(1, 0, 0);
              LOADB(0, 2, 0);        WAITL(4);     MM(1, 1, 1);
    LOADA(1); STG(2); LOADB(1, 2, 1); WAITV(4, 4); MM(0, 0, 0);
              LOADB(0, 3, 0);        WAITL(4);     MM(0, 1, 1);
    LOADA(0); STG(3); LOADB(1, 3, 1); WAITV(4, 4); MM(1, 0, 0);
              LOADB(0, 4, 0);        WAITL(4);     MM(1, 1, 1);
    LOADA(1); STG(4); LOADB(1, 4, 1); WAITV(4, 4); MM(0, 0, 0);
              LOADB(0, 5, 0);        WAITL(4);     MM(0, 1, 1);
    LOADA(0); STG(5); LOADB(1, 5, 1); WAITV(4, 4); MM(1, 0, 0);
              LOADB(0, 6, 0);        WAITL(4);     MM(1, 1, 1);
    LOADA(1); STG(6); LOADB(1, 6, 1); WAITV(4, 4); MM(0, 0, 0);
              LOADB(0, 7, 0);        WAITL(4);     MM(0, 1, 1);
    // t=7: no STG; drain {S5, A7x2}, leave {S6, A8x2}
    LOADA(0);         LOADB(1, 7, 1); WAITV(3, 4); MM(1, 0, 0);
              LOADB(0, 8, 0);        WAITL(4);     MM(1, 1, 1);
    // t=8: prefetch next cc's A(0); drain {S6, A8x2} pre-barrier, leave A0'x2 in flight
    LOADA(1);         LOADB(1, 8, 1); WAITV(2, 4); MM(0, 0, 0);
                                     WAITV(2, 0);  MM(0, 1, 1);
    __builtin_amdgcn_s_barrier();
    { const char* tmp = lbuf; lbuf = (const char*)stb; stb = (char*)tmp; }
    { short8 t0 = afr1[0]; afr0[0] = t0; t0 = afr1[1]; afr0[1] = t0; }
  }
  // peeled cc = 7 (no staging, no barrier)
  {
    LOADB(0, 0, 0);
    LOADA(1); LOADB(1, 0, 1); WAITV(2, 4); MM(0, 0, 0);
              LOADB(0, 1, 0); WAITL(4);    MM(0, 1, 1);
    LOADA(0); LOADB(1, 1, 1); WAITV(2, 4); MM(1, 0, 0);
              LOADB(0, 2, 0); WAITL(4);    MM(1, 1, 1);
    LOADA(1); LOADB(1, 2, 1); WAITV(2, 4); MM(0, 0, 0);
              LOADB(0, 3, 0); WAITL(4);    MM(0, 1, 1);
    LOADA(0); LOADB(1, 3, 1); WAITV(2, 4); MM(1, 0, 0);
              LOADB(0, 4, 0); WAITL(4);    MM(1, 1, 1);
    LOADA(1); LOADB(1, 4, 1); WAITV(2, 4); MM(0, 0, 0);
              LOADB(0, 5, 0); WAITL(4);    MM(0, 1, 1);
    LOADA(0); LOADB(1, 5, 1); WAITV(2, 4); MM(1, 0, 0);
              LOADB(0, 6, 0); WAITL(4);    MM(1, 1, 1);
    LOADA(1); LOADB(1, 6, 1); WAITV(2, 4); MM(0, 0, 0);
              LOADB(0, 7, 0); WAITL(4);    MM(0, 1, 1);
    LOADA(0); LOADB(1, 7, 1); WAITV(2, 4); MM(1, 0, 0);
              LOADB(0, 8, 0); WAITL(4);    MM(1, 1, 1);
              LOADB(1, 8, 1); WAITV(0, 4); MM(0, 0, 0);
                              WAITL(0);    MM(0, 1, 1);
  }

  // epilogue: bias + instance-norm + blend; C/D: col=lane&15, row=(lane>>4)*4+reg
  #pragma unroll
  for (int mf = 0; mf < 2; ++mf) {
    int vbase = vfpair * 32 + mf * 16 + hi * 4;
    #pragma unroll
    for (int p = 0; p < 2; ++p) {
      int c = (vbase >> 1) + p;
      float bg = bias[c], bb = bias[256 + c];
      float mean = stats[b * 256 + c], rs = stats[1024 + b * 256 + c];
      const float* xrow = x + ((size_t)(b * 256 + c) * 128 + h0) * 256 + w0;
      float* orow = out + ((size_t)(b * 256 + c) * 128 + h0) * 256 + w0;
      #pragma unroll
      for (int nf = 0; nf < 8; ++nf) {
        int pix = nf * 16 + lo;
        float g  = acc[mf][nf][2 * p]     + bg;
        float bt = acc[mf][nf][2 * p + 1] + bb;
        float xv = xrow[pix];
        orow[pix] = (xv - mean) * rs * (1.f + g) + bt;
      }
    }
  }
}

extern "C" void kernel_launch(void* const* d_in, const int* in_sizes, int n_in,
                              void* d_out, int out_size, void* d_ws, size_t ws_size,
                              hipStream_t stream)
{
  const float* x    = (const float*)d_in[0];
  const int*   seg  = (const int*)d_in[1];
  const float* sty  = (const float*)d_in[2];
  const float* fcw  = (const float*)d_in[3];
  const float* fcb  = (const float*)d_in[4];
  const float* cgw  = (const float*)d_in[5];
  const float* cgb  = (const float*)d_in[6];
  const float* cbw  = (const float*)d_in[7];
  const float* cbb  = (const float*)d_in[8];
  const float* mlpw = (const float*)d_in[9];
  const float* mlpb = (const float*)d_in[10];
  const float* sgw  = (const float*)d_in[11];
  const float* sgb  = (const float*)d_in[12];
  const float* sbw  = (const float*)d_in[13];
  const float* sbb  = (const float*)d_in[14];
  const float* blg  = (const float*)d_in[15];
  const float* blb  = (const float*)d_in[16];
  float* out = (float*)d_out;

  char* ws = (char*)d_ws;
  const size_t U_BYTES = (size_t)4 * HP * WPAD * CIN * 2;   // 68,689,920
  size_t off = 0;
  unsigned short* U = (unsigned short*)(ws + off); off += U_BYTES + 262144;  // pad: overshoot reads
  char* Wp   = ws + off;           off += (size_t)512 * 256 * 9 * 2;  // 2,359,296
  float* mu  = (float*)(ws + off); off += (size_t)4 * 35 * 128 * 4;   // 71,680
  float* mlpT= (float*)(ws + off); off += (size_t)35 * 9 * 128 * 4;   // 161,280
  float* bias= (float*)(ws + off); off += 2048;
  float* stats=(float*)(ws + off); off += 8192;
  if (ws_size < off) return;

  k_pre <<<dim3(298),   dim3(256), 0, stream>>>(
      sty, fcw, fcb, mu, mlpw, mlpT, cgb, cbb, sgb, sbb, blg, blb, bias);
  k_mid <<<dim3(18371), dim3(256), 0, stream>>>(
      x, stats, seg, mu, mlpT, mlpb, U, cgw, cbw, sgw, sbw, blg, blb,
      (unsigned short*)Wp);
  k_conv<<<dim3(4096),  dim3(256), 0, stream>>>(
      x, (const uint4*)U, Wp, bias, stats, out);
}

// Round 13
// 326.441 us; speedup vs baseline: 1.1728x; 1.0318x over previous
//
#include <hip/hip_runtime.h>
#include <stdint.h>

typedef __attribute__((ext_vector_type(8))) short short8;
typedef __attribute__((ext_vector_type(4))) float f32x4;

#define HP 130
#define WPAD 258
#define CIN 256

#define AS1 __attribute__((address_space(1)))
#define AS3 __attribute__((address_space(3)))

__device__ __forceinline__ unsigned short f2bf(float f) {
  unsigned int x = __float_as_uint(f);
  x = x + 0x7fffu + ((x >> 16) & 1u);
  return (unsigned short)(x >> 16);
}

// ================= k1: mu-FC | mlpT+bias  (only true upstream deps of build) ===========
// Blocks: [0,140) mu   [140,298) prep
__global__ __launch_bounds__(256) void k_pre(
    const float* __restrict__ sty, const float* __restrict__ fcw,
    const float* __restrict__ fcb, float* __restrict__ mu,
    const float* __restrict__ mlpw, float* __restrict__ mlpT,
    const float* __restrict__ cgb, const float* __restrict__ cbb,
    const float* __restrict__ sgb, const float* __restrict__ sbb,
    const float* __restrict__ blg, const float* __restrict__ blb,
    float* __restrict__ bias)
{
  int bid = blockIdx.x, tid = threadIdx.x;
  if (bid < 140) {
    int b = bid / 35, j = bid - 35 * b;
    __shared__ float ss[128];
    if (tid < 128) ss[tid] = sty[((size_t)b * 35 + j) * 128 + tid];
    __syncthreads();
    if (tid < 128) {
      int o = tid;
      const float4* wr = (const float4*)(fcw + ((size_t)j * 128 + o) * 128);
      const float4* sv = (const float4*)ss;
      float acc = fcb[j * 128 + o];
      #pragma unroll 8
      for (int d = 0; d < 32; ++d) {
        float4 wv = wr[d], s4 = sv[d];
        acc += wv.x * s4.x + wv.y * s4.y + wv.z * s4.z + wv.w * s4.w;
      }
      mu[((size_t)b * 35 + j) * 128 + o] = fmaxf(acc, 0.f);
    }
  } else {
    int t = (bid - 140) * 256 + tid;
    if (t < 40320) {
      int o = t & 127;
      int jt = t >> 7;                    // j*9 + tap
      mlpT[(size_t)jt * 128 + o] = mlpw[((size_t)o * 35 + (jt / 9)) * 9 + (jt % 9)];
    }
    if (t < 256) {
      float ga = 1.f / (1.f + expf(-blg[0]));
      float ba = 1.f / (1.f + expf(-blb[0]));
      bias[t]       = ga * cgb[t] + (1.f - ga) * sgb[t];
      bias[256 + t] = ba * cbb[t] + (1.f - ba) * sbb[t];
    }
  }
}

// ================= k2: IN-stats | build U | halo-zero | weight-pack  (all independent) ==
// Blocks: [0,1024) stats   [1024,17408) build   [17408,17795) halo   [17795,18371) pack
__global__ __launch_bounds__(256) void k_mid(
    const float* __restrict__ x, float* __restrict__ stats,
    const int* __restrict__ seg, const float* __restrict__ mu,
    const float* __restrict__ mlpT, const float* __restrict__ mlpb,
    unsigned short* __restrict__ U,
    const float* __restrict__ cgw, const float* __restrict__ cbw,
    const float* __restrict__ sgw, const float* __restrict__ sbw,
    const float* __restrict__ blg, const float* __restrict__ blb,
    unsigned short* __restrict__ Wp)
{
  int bid = blockIdx.x, t = threadIdx.x;
  if (bid < 1024) {
    int bc = bid;
    const float* p = x + (size_t)bc * 32768;
    float s = 0.f, s2 = 0.f;
    #pragma unroll 4
    for (int i = 0; i < 32; ++i) {
      float4 v = *(const float4*)(p + (size_t)i * 1024 + t * 4);
      s  += v.x + v.y + v.z + v.w;
      s2 += v.x * v.x + v.y * v.y + v.z * v.z + v.w * v.w;
    }
    #pragma unroll
    for (int off2 = 32; off2 > 0; off2 >>= 1) {
      s  += __shfl_down(s, off2);
      s2 += __shfl_down(s2, off2);
    }
    __shared__ float red[8];
    int lane = t & 63, wv = t >> 6;
    if (lane == 0) { red[wv] = s; red[4 + wv] = s2; }
    __syncthreads();
    if (t == 0) {
      float S  = red[0] + red[1] + red[2] + red[3];
      float S2 = red[4] + red[5] + red[6] + red[7];
      float mean = S * (1.f / 32768.f);
      float var  = S2 * (1.f / 32768.f) - mean * mean;
      stats[bc] = mean;
      stats[1024 + bc] = rsqrtf(var + 1e-5f);
    }
  } else if (bid < 17408) {
    int blk = bid - 1024;               // 16384
    int b = blk >> 12, rem = blk & 4095;
    int h = rem >> 5, w0 = (rem & 31) << 3;
    int p = t >> 5, q = t & 31;
    int w = w0 + p;
    unsigned short* up = U + (((size_t)(b * HP + h + 1)) * WPAD + (w + 1)) * CIN;
    union { uint4 v4; unsigned short s[8]; } u;
    if (q < 16) {
      int lab = seg[((size_t)b * 128 + h) * 256 + w];
      const float4* mrow = (const float4*)(mu + ((size_t)(b * 35 + lab)) * 128 + q * 8);
      float4 v0 = mrow[0], v1 = mrow[1];
      u.s[0] = f2bf(v0.x); u.s[1] = f2bf(v0.y); u.s[2] = f2bf(v0.z); u.s[3] = f2bf(v0.w);
      u.s[4] = f2bf(v1.x); u.s[5] = f2bf(v1.y); u.s[6] = f2bf(v1.z); u.s[7] = f2bf(v1.w);
      *(uint4*)(up + q * 8) = u.v4;
    } else {
      int o0 = (q - 16) * 8;
      float a[8];
      #pragma unroll
      for (int j = 0; j < 8; ++j) a[j] = mlpb[o0 + j];
      #pragma unroll
      for (int kh = 0; kh < 3; ++kh) {
        int hh = h + kh - 1;
        if ((unsigned)hh < 128u) {
          #pragma unroll
          for (int kw = 0; kw < 3; ++kw) {
            int ww = w + kw - 1;
            if ((unsigned)ww < 256u) {
              int lab2 = seg[((size_t)b * 128 + hh) * 256 + ww];
              const float4* wr = (const float4*)(mlpT + ((size_t)lab2 * 9 + kh * 3 + kw) * 128 + o0);
              float4 v0 = wr[0], v1 = wr[1];
              a[0] += v0.x; a[1] += v0.y; a[2] += v0.z; a[3] += v0.w;
              a[4] += v1.x; a[5] += v1.y; a[6] += v1.z; a[7] += v1.w;
            }
          }
        }
      }
      #pragma unroll
      for (int j = 0; j < 8; ++j) u.s[j] = f2bf(fmaxf(a[j], 0.f));
      *(uint4*)(up + 128 + o0) = u.v4;
    }
  } else if (bid < 17795) {
    int tt = (bid - 17408) * 256 + t;
    if (tt >= 98816) return;            // 3088 halo pixels * 32 uint4
    int sub = tt & 31, pi = tt >> 5;
    int b = pi / 772, r = pi - b * 772;
    int h, w;
    if (r < 258)      { h = 0;   w = r; }
    else if (r < 516) { h = 129; w = r - 258; }
    else if (r < 644) { h = r - 516 + 1; w = 0; }
    else              { h = r - 644 + 1; w = 257; }
    ((uint4*)U)[((size_t)(b * HP + h) * WPAD + w) * 32 + sub] = (uint4){0, 0, 0, 0};
  } else {
    // ---- packed, blended bf16 weights: [vfgrp(8)][cc(8)][tap(9)][mf(4)][lane(64)] x16B
    // vf = vfgrp*4+mf; v = vf*16+(lane&15); k-index = cc*32 + 8*(lane>>4) + j
    int gid = (bid - 17795) * 256 + t;  // 147456 exactly
    int lane = gid & 63;
    int cc = (gid >> 6) & 7;
    int rest = gid >> 9;                // vf*9 + tap
    int tap = rest % 9;
    int vf = rest / 9;
    int v = vf * 16 + (lane & 15);
    int c = v >> 1, g = v & 1;
    int ci0 = cc * 32 + (lane >> 4) * 8;
    float ga = 1.f / (1.f + expf(-blg[0]));
    float ba = 1.f / (1.f + expf(-blb[0]));
    float sc = g ? ba : ga;
    const float* wavg = g ? cbw : cgw;
    const float* wsp  = g ? sbw : sgw;
    union { uint4 v4; unsigned short s[8]; } u;
    #pragma unroll
    for (int jj = 0; jj < 8; ++jj) {
      int ci = ci0 + jj;
      float val;
      if (ci < 128) val = sc * wavg[((size_t)c * 128 + ci) * 9 + tap];
      else          val = (1.f - sc) * wsp[((size_t)c * 128 + (ci - 128)) * 9 + tap];
      u.s[jj] = f2bf(val);
    }
    int vfgrp = vf >> 2, mfi = vf & 3;
    uint4* dst = (uint4*)Wp + ((size_t)(((vfgrp * 8 + cc) * 9 + tap) * 4 + mfi)) * 64 + lane;
    *dst = u.v4;
  }
}

// ---------------- main fused conv: 4 waves x (64v x 128px) = 256v x 128px per block ----
// Best measured: 257 µs, MfmaUtil 55%. Counted vmcnt: per-tap waits allow
// {STG(t-1), A(t)x4, STG(t)} outstanding -> every HBM staging load gets a >=2-tap
// (~1200 cyc) window; never drains mid-loop.
// __launch_bounds__(256,2): acc(128 AGPR) + arch(128 VGPR) = full 256/wave; (256,3)
// spills (R6: 6.2 GB scratch). V=64 is forced: V=32 hits the LDS-read wall (R12),
// P=64 hits the vmem-return wall (R4), 32x32 MFMA is slower (R8).

#define WAITV_(vm, lg) asm volatile("s_waitcnt vmcnt(" #vm ") lgkmcnt(" #lg ")" ::: "memory")
#define WAITV(vm, lg) do { WAITV_(vm, lg); __builtin_amdgcn_sched_barrier(0); } while (0)
#define WAITL(lg) do { asm volatile("s_waitcnt lgkmcnt(" #lg ")" ::: "memory"); __builtin_amdgcn_sched_barrier(0); } while (0)

#define MM(AS, BS, H) do {                                                     \
    __builtin_amdgcn_s_setprio(1);                                             \
    _Pragma("unroll")                                                          \
    for (int mf_ = 0; mf_ < 4; ++mf_)                                          \
      _Pragma("unroll")                                                        \
      for (int nf_ = 0; nf_ < 4; ++nf_)                                        \
        acc[mf_][(H) * 4 + nf_] = __builtin_amdgcn_mfma_f32_16x16x32_bf16(     \
            afr##AS[mf_], bfr##BS[nf_], acc[mf_][(H) * 4 + nf_], 0, 0, 0);     \
    __builtin_amdgcn_s_setprio(0);                                             \
  } while (0)

#define LOADA(NS) do {                                                         \
    aptr += 4096;                                                              \
    afr##NS[0] = *(const short8*)(aptr);                                       \
    afr##NS[1] = *(const short8*)(aptr + 1024);                                \
    afr##NS[2] = *(const short8*)(aptr + 2048);                                \
    afr##NS[3] = *(const short8*)(aptr + 3072);                                \
  } while (0)

#define LOADB(NS, T, H) do {                                                   \
    bfr##NS[0] = *(const short8*)(lbuf + off[T] + (H) * 4096);                 \
    bfr##NS[1] = *(const short8*)(lbuf + off[T] + (H) * 4096 + 1024);          \
    bfr##NS[2] = *(const short8*)(lbuf + off[T] + (H) * 4096 + 2048);          \
    bfr##NS[3] = *(const short8*)(lbuf + off[T] + (H) * 4096 + 3072);          \
  } while (0)

#define STG(SI) do {                                                           \
    __builtin_amdgcn_global_load_lds((const AS1 unsigned int*)gsrc[SI],        \
        (AS3 unsigned int*)((SI) < 6 ? (stbw + (SI) * 4096) : (stb + 24576)),  \
        16, 0, 0);                                                             \
    gsrc[SI] += 64;                                                            \
  } while (0)

__global__ __launch_bounds__(256, 2) void k_conv(
    const float* __restrict__ x, const uint4* __restrict__ U,
    const char* __restrict__ Wp, const float* __restrict__ bias,
    const float* __restrict__ stats, float* __restrict__ out)
{
  int bid = blockIdx.x;                // 2048
  int xcd = bid & 7, i0 = bid >> 3;    // i0: 0..255
  int pt = xcd * 128 + (i0 >> 1);      // mt fastest within an XCD
  int mt = i0 & 1;
  int b = pt >> 8, rem = pt & 255;
  int h0 = rem >> 1, w0 = (rem & 1) << 7;
  int tid = threadIdx.x;
  int lane = tid & 63, wid = tid >> 6;
  int lo = lane & 15, hi = lane >> 4;

  __shared__ uint4 Ubuf[2][1600];   // 25 rows of 1 KB (+pad) per buffer

  // staging source addresses; row_i = (i<6) ? wid+4*i : 24 (row 24 issued by ALL waves)
  const char* gsrc[7];
  #pragma unroll
  for (int i = 0; i < 7; ++i) {
    int row = (i < 6) ? (wid + 4 * i) : 24;
    int slot = row * 64 + lane;
    int P = slot >> 2, sp = slot & 3;
    int sl = sp ^ ((P >> 1) & 3);
    int r = P / 130, pix = P - r * 130;     // r==3 only for row-24 pad lanes (U over-alloc'd)
    gsrc[i] = (const char*)U +
        (size_t)(((b * HP + h0 + r) * WPAD + (w0 + pix)) * CIN + sl * 8) * 2;
  }

  f32x4 acc[4][8];
  #pragma unroll
  for (int i = 0; i < 4; ++i)
    #pragma unroll
    for (int j = 0; j < 8; ++j) acc[i][j] = (f32x4){0.f, 0.f, 0.f, 0.f};

  // A stream: sequential 4 KB per (cc,tap); each wave owns vfgrp = mt*4 + wid
  int vfgrp = mt * 4 + wid;
  const char* aptr = Wp + (size_t)vfgrp * 294912 + lane * 16;

  // B read offsets per tap (pixel base = lo; nf adds 1024 B; swizzle invariant in nf)
  int off[9];
  #pragma unroll
  for (int t = 0; t < 9; ++t) {
    int Pb = (t / 3) * 130 + (t % 3) + lo;
    off[t] = Pb * 64 + ((hi ^ ((Pb >> 1) & 3)) << 4);
  }

  const char* lbuf = (const char*)&Ubuf[0][0];
  char* stb = (char*)&Ubuf[1][0];

  // prologue: stage buffer 0 (cc=0), then A(0)
  {
    char* stb0 = (char*)&Ubuf[0][0];
    char* stbw0 = stb0 + wid * 1024;
    #pragma unroll
    for (int i = 0; i < 7; ++i) {
      __builtin_amdgcn_global_load_lds((const AS1 unsigned int*)gsrc[i],
          (AS3 unsigned int*)(i < 6 ? (stbw0 + i * 4096) : (stb0 + 24576)), 16, 0, 0);
      gsrc[i] += 64;
    }
  }
  short8 afr0[4], afr1[4], bfr0[4], bfr1[4];
  afr0[0] = *(const short8*)(aptr);
  afr0[1] = *(const short8*)(aptr + 1024);
  afr0[2] = *(const short8*)(aptr + 2048);
  afr0[3] = *(const short8*)(aptr + 3072);
  WAITV(4, 0);                      // 7 stage rows done; A(0) may stay in flight
  __builtin_amdgcn_s_barrier();

  #pragma unroll 1
  for (int cc = 0; cc < 7; ++cc) {
    char* stbw = stb + wid * 1024;
    LOADB(0, 0, 0);
    // t=0: force A(0)@prev done; allow {A(1)x4, STG0}
    LOADA(1); STG(0); LOADB(1, 0, 1); WAITV(5, 4); MM(0, 0, 0);
              LOADB(0, 1, 0);        WAITL(4);     MM(0, 1, 1);
    // t=1..6: force A(t)@prev done; allow {STG(t-1), A(t+1)x4, STG(t)} -> 2-tap STG window
    LOADA(0); STG(1); LOADB(1, 1, 1); WAITV(6, 4); MM(1, 0, 0);
              LOADB(0, 2, 0);        WAITL(4);     MM(1, 1, 1);
    LOADA(1); STG(2); LOADB(1, 2, 1); WAITV(6, 4); MM(0, 0, 0);
              LOADB(0, 3, 0);        WAITL(4);     MM(0, 1, 1);
    LOADA(0); STG(3); LOADB(1, 3, 1); WAITV(6, 4); MM(1, 0, 0);
              LOADB(0, 4, 0);        WAITL(4);     MM(1, 1, 1);
    LOADA(1); STG(4); LOADB(1, 4, 1); WAITV(6, 4); MM(0, 0, 0);
              LOADB(0, 5, 0);        WAITL(4);     MM(0, 1, 1);
    LOADA(0); STG(5); LOADB(1, 5, 1); WAITV(6, 4); MM(1, 0, 0);
              LOADB(0, 6, 0);        WAITL(4);     MM(1, 1, 1);
    LOADA(1); STG(6); LOADB(1, 6, 1); WAITV(6, 4); MM(0, 0, 0);
              LOADB(0, 7, 0);        WAITL(4);     MM(0, 1, 1);
    // t=7: no STG; allow {STG6, A(8)x4}
    LOADA(0);         LOADB(1, 7, 1); WAITV(5, 4); MM(1, 0, 0);
              LOADB(0, 8, 0);        WAITL(4);     MM(1, 1, 1);
    // t=8: prefetch next cc's A(0); vm(4) forces A(8) + all STGs done pre-barrier
    LOADA(1);         LOADB(1, 8, 1); WAITV(4, 4); MM(0, 0, 0);
                                     WAITV(4, 0);  MM(0, 1, 1);
    __builtin_amdgcn_s_barrier();
    { const char* tmp = lbuf; lbuf = (const char*)stb; stb = (char*)tmp; }
    { short8 t0 = afr1[0]; afr0[0] = t0; t0 = afr1[1]; afr0[1] = t0;
      t0 = afr1[2]; afr0[2] = t0; t0 = afr1[3]; afr0[3] = t0; }
  }
  // peeled cc = 7 (no staging, no barrier)
  {
    LOADB(0, 0, 0);
    LOADA(1); LOADB(1, 0, 1); WAITV(4, 4); MM(0, 0, 0);
              LOADB(0, 1, 0); WAITL(4);    MM(0, 1, 1);
    LOADA(0); LOADB(1, 1, 1); WAITV(4, 4); MM(1, 0, 0);
              LOADB(0, 2, 0); WAITL(4);    MM(1, 1, 1);
    LOADA(1); LOADB(1, 2, 1); WAITV(4, 4); MM(0, 0, 0);
              LOADB(0, 3, 0); WAITL(4);    MM(0, 1, 1);
    LOADA(0); LOADB(1, 3, 1); WAITV(4, 4); MM(1, 0, 0);
              LOADB(0, 4, 0); WAITL(4);    MM(1, 1, 1);
    LOADA(1); LOADB(1, 4, 1); WAITV(4, 4); MM(0, 0, 0);
              LOADB(0, 5, 0); WAITL(4);    MM(0, 1, 1);
    LOADA(0); LOADB(1, 5, 1); WAITV(4, 4); MM(1, 0, 0);
              LOADB(0, 6, 0); WAITL(4);    MM(1, 1, 1);
    LOADA(1); LOADB(1, 6, 1); WAITV(4, 4); MM(0, 0, 0);
              LOADB(0, 7, 0); WAITL(4);    MM(0, 1, 1);
    LOADA(0); LOADB(1, 7, 1); WAITV(4, 4); MM(1, 0, 0);
              LOADB(0, 8, 0); WAITL(4);    MM(1, 1, 1);
              LOADB(1, 8, 1); WAITV(0, 4); MM(0, 0, 0);
                              WAITL(0);    MM(0, 1, 1);
  }

  // epilogue: bias + instance-norm + blend; C/D: col=lane&15, row=(lane>>4)*4+reg
  #pragma unroll
  for (int mf = 0; mf < 4; ++mf) {
    int vbase = mt * 256 + wid * 64 + mf * 16 + hi * 4;
    #pragma unroll
    for (int p = 0; p < 2; ++p) {
      int c = (vbase >> 1) + p;
      float bg = bias[c], bb = bias[256 + c];
      float mean = stats[b * 256 + c], rs = stats[1024 + b * 256 + c];
      const float* xrow = x + ((size_t)(b * 256 + c) * 128 + h0) * 256 + w0;
      float* orow = out + ((size_t)(b * 256 + c) * 128 + h0) * 256 + w0;
      #pragma unroll
      for (int nf = 0; nf < 8; ++nf) {
        int pix = nf * 16 + lo;
        float g  = acc[mf][nf][2 * p]     + bg;
        float bt = acc[mf][nf][2 * p + 1] + bb;
        float xv = xrow[pix];
        orow[pix] = (xv - mean) * rs * (1.f + g) + bt;
      }
    }
  }
}

extern "C" void kernel_launch(void* const* d_in, const int* in_sizes, int n_in,
                              void* d_out, int out_size, void* d_ws, size_t ws_size,
                              hipStream_t stream)
{
  const float* x    = (const float*)d_in[0];
  const int*   seg  = (const int*)d_in[1];
  const float* sty  = (const float*)d_in[2];
  const float* fcw  = (const float*)d_in[3];
  const float* fcb  = (const float*)d_in[4];
  const float* cgw  = (const float*)d_in[5];
  const float* cgb  = (const float*)d_in[6];
  const float* cbw  = (const float*)d_in[7];
  const float* cbb  = (const float*)d_in[8];
  const float* mlpw = (const float*)d_in[9];
  const float* mlpb = (const float*)d_in[10];
  const float* sgw  = (const float*)d_in[11];
  const float* sgb  = (const float*)d_in[12];
  const float* sbw  = (const float*)d_in[13];
  const float* sbb  = (const float*)d_in[14];
  const float* blg  = (const float*)d_in[15];
  const float* blb  = (const float*)d_in[16];
  float* out = (float*)d_out;

  char* ws = (char*)d_ws;
  const size_t U_BYTES = (size_t)4 * HP * WPAD * CIN * 2;   // 68,689,920
  size_t off = 0;
  unsigned short* U = (unsigned short*)(ws + off); off += U_BYTES + 262144;  // pad: row-24 overshoot reads
  char* Wp   = ws + off;           off += (size_t)512 * 256 * 9 * 2;  // 2,359,296
  float* mu  = (float*)(ws + off); off += (size_t)4 * 35 * 128 * 4;   // 71,680
  float* mlpT= (float*)(ws + off); off += (size_t)35 * 9 * 128 * 4;   // 161,280
  float* bias= (float*)(ws + off); off += 2048;
  float* stats=(float*)(ws + off); off += 8192;
  if (ws_size < off) return;

  k_pre <<<dim3(298),   dim3(256), 0, stream>>>(
      sty, fcw, fcb, mu, mlpw, mlpT, cgb, cbb, sgb, sbb, blg, blb, bias);
  k_mid <<<dim3(18371), dim3(256), 0, stream>>>(
      x, stats, seg, mu, mlpT, mlpb, U, cgw, cbw, sgw, sbw, blg, blb,
      (unsigned short*)Wp);
  k_conv<<<dim3(2048),  dim3(256), 0, stream>>>(
      x, (const uint4*)U, Wp, bias, stats, out);
}